// Round 11
// baseline (243.981 us; speedup 1.0000x reference)
//
#include <hip/hip_runtime.h>

// CapsuleLayer dynamic routing, MI355X. R14: 8b/wave, no bh-split.
//  - R13 accounting: sweeps ~42us vs ~12-16us floor. Two quantified wastes:
//    (1) 4b/wave + bh-split => 8 waves/CU each read the whole 32KB tile
//        (256KB LDS reads per CU-iter, 2x the FMA time);
//    (2) bh-split => every W tile streamed from HBM twice (XCD co-location
//        never materialized, R12).
//  - R14: block = 4 waves x 8 b = all 32 b; grid 512 igs (IC=4); 2 blocks/CU.
//    Per k one ds_read_b128 pair feeds 64 FMA (4:1); W fetched once/sweep.
//  - VGPR discipline: PASS0 accumulates into facc directly (~110 regs);
//    PASS1/2 drop the persistent as_ array -- act re-loaded from L2 in the
//    epilogue (~180 regs, no forced cap). PASS2's act0+act1 precomputed by
//    the round-1 reduce (actsum) via dot-linearity of logits.
//  - x s_loads hoisted to k-half boundaries, BEFORE the ds windows (R7's
//    lgkm-poison avoided). W windows: k-quarter, 8 independent ds_read_b128
//    into named float4 regs, then the FMA block (R13's proven idiom).
//  - Staging: R5's glds dwordx4 dbuf w/ pre-swizzled source, 1 barrier/iter.
//
// Lane layout: lane l owns d=l>>1, h=l&1, o = d*16+h*8+j (j=0..7), for 8 b's.
// a-half combine: shfl_xor(1); softmax over D: shfl_xor {2,4,8,16,32}.
// LDS W layout (per half): float idx = jq*4096 + k*256 + (d*2+h)*4 + (j&3).

#define B_  32
#define I_  2048
#define K_  16
#define O_  512
#define NG_ 512   // i-groups (partial leading dim)
#define IC_ 4     // i's per group

#define GLB(p)  ((const __attribute__((address_space(1))) void*)(p))
#define LDSP(p) ((__attribute__((address_space(3))) void*)(p))

template<int PASS>
__global__ __launch_bounds__(256, 2)
void sweep_kernel(const float* __restrict__ x, const float* __restrict__ W,
                  const float* __restrict__ act_g, float* __restrict__ partial)
{
    const int tid  = threadIdx.x;
    const int lane = tid & 63;
    const int wave = tid >> 6;              // 0..3
    const int ig   = blockIdx.x;            // 0..511
    const int d    = lane >> 1;             // 0..31
    const int h    = lane & 1;
    const int obase = d * 16 + h * 8;       // lane's first o

    // wave-uniform batch base (8 b's per wave, 4 waves = 32 b)
    const int wv = __builtin_amdgcn_readfirstlane(wave);
    const int b0 = wv * 8;

    __shared__ float sW[2][K_ * O_];        // 2 x 32 KB permuted W tiles

    // pre-swizzled glds source offsets: slot s -> global float4 f (bijection)
    int voff[8];
    #pragma unroll
    for (int c = 0; c < 8; ++c) {
        const int s = c * 256 + wave * 64 + lane;
        const int f = ((s >> 10) & 1) | ((s & 1) << 1)
                    | (((s >> 1) & 31) << 2) | (((s >> 6) & 15) << 7);
        voff[c] = f << 4;
    }

    float facc[8][8];
    #pragma unroll
    for (int bb = 0; bb < 8; ++bb)
        #pragma unroll
        for (int j = 0; j < 8; ++j) facc[bb][j] = 0.f;

    // prologue: stage W[ig*IC] into buf 0
    {
        const char* gb = (const char*)(W + (size_t)(ig * IC_) * (K_ * O_));
        #pragma unroll
        for (int c = 0; c < 8; ++c)
            __builtin_amdgcn_global_load_lds(GLB(gb + voff[c]),
                LDSP(&sW[0][(c * 256 + wave * 64) * 4]), 16, 0, 0);
    }

    #pragma unroll 1
    for (int ii = 0; ii < IC_; ++ii) {
        const int i = ig * IC_ + ii;
        __syncthreads();   // implicit vmcnt(0): buf[ii&1] staged; reads done
        if (ii + 1 < IC_) {
            const char* gb = (const char*)(W + (size_t)(i + 1) * (K_ * O_));
            float* nbuf = sW[(ii + 1) & 1];
            #pragma unroll
            for (int c = 0; c < 8; ++c)
                __builtin_amdgcn_global_load_lds(GLB(gb + voff[c]),
                    LDSP(&nbuf[(c * 256 + wave * 64) * 4]), 16, 0, 0);
        }
        const float* cbuf = sW[ii & 1];

        float V[8][8];
        if (PASS >= 1) {
            #pragma unroll
            for (int bb = 0; bb < 8; ++bb)
                #pragma unroll
                for (int j = 0; j < 8; ++j) V[bb][j] = 0.f;
        }

        #pragma unroll
        for (int kh = 0; kh < 2; ++kh) {
            // x for this k-half: 8 b x 8 k, wave-uniform -> SGPRs, loaded
            // BEFORE any ds_read of this half (no lgkm interleave poison)
            float xs[8][8];
            #pragma unroll
            for (int bb = 0; bb < 8; ++bb) {
                const float4* xp = (const float4*)(x + ((size_t)(b0 + bb) * I_ + i) * K_ + kh * 8);
                const float4 u0 = xp[0], u1 = xp[1];
                xs[bb][0]=u0.x; xs[bb][1]=u0.y; xs[bb][2]=u0.z; xs[bb][3]=u0.w;
                xs[bb][4]=u1.x; xs[bb][5]=u1.y; xs[bb][6]=u1.z; xs[bb][7]=u1.w;
            }
            #pragma unroll
            for (int kq = 0; kq < 2; ++kq) {
                // window: 8 independent ds_read_b128 into named regs
                float4 wr0[4], wr1[4];
                #pragma unroll
                for (int t = 0; t < 4; ++t) {
                    const int k = kh * 8 + kq * 4 + t;
                    wr0[t] = *(const float4*)&cbuf[k * 256 + lane * 4];
                    wr1[t] = *(const float4*)&cbuf[4096 + k * 256 + lane * 4];
                }
                #pragma unroll
                for (int t = 0; t < 4; ++t) {
                    const float w[8] = {wr0[t].x, wr0[t].y, wr0[t].z, wr0[t].w,
                                        wr1[t].x, wr1[t].y, wr1[t].z, wr1[t].w};
                    #pragma unroll
                    for (int bb = 0; bb < 8; ++bb) {
                        const float xb = xs[bb][kq * 4 + t];
                        #pragma unroll
                        for (int j = 0; j < 8; ++j) {
                            if (PASS == 0) facc[bb][j] = fmaf(xb, w[j], facc[bb][j]);
                            else           V[bb][j]    = fmaf(xb, w[j], V[bb][j]);
                        }
                    }
                }
            }
        }

        if (PASS >= 1) {
            #pragma unroll
            for (int bb = 0; bb < 8; ++bb) {
                // act re-loaded from L2 each iter (saves 64 persistent VGPRs)
                const float4* ap = (const float4*)(act_g + (b0 + bb) * O_ + obase);
                const float4 a0 = ap[0], a1 = ap[1];
                const float a[8] = {a0.x, a0.y, a0.z, a0.w, a1.x, a1.y, a1.z, a1.w};
                float p0 = 0.f;
                #pragma unroll
                for (int j = 0; j < 8; ++j) p0 = fmaf(V[bb][j], a[j], p0);
                p0 += __shfl_xor(p0, 1);        // combine the two a-halves
                // softmax over 32 d's (no max-sub: |logits| small, f32-safe)
                const float e = __expf(p0);
                float s = e;
                s += __shfl_xor(s, 2);
                s += __shfl_xor(s, 4);
                s += __shfl_xor(s, 8);
                s += __shfl_xor(s, 16);
                s += __shfl_xor(s, 32);
                const float r = e * __builtin_amdgcn_rcpf(s);
                #pragma unroll
                for (int j = 0; j < 8; ++j)
                    facc[bb][j] = fmaf(r, V[bb][j], facc[bb][j]);
            }
        }
    }

    // flush partial[ig][b][o]
    #pragma unroll
    for (int bb = 0; bb < 8; ++bb) {
        float4* dst = (float4*)(partial + ((size_t)ig * B_ + b0 + bb) * O_ + obase);
        dst[0] = make_float4(facc[bb][0], facc[bb][1], facc[bb][2], facc[bb][3]);
        dst[1] = make_float4(facc[bb][4], facc[bb][5], facc[bb][6], facc[bb][7]);
    }
}

// sum NG_ partials -> *scale + bias -> squash over A -> out.
// If prev!=null also emit outsum = out + prev (act0+act1 for PASS2's fold).
// 512 wgs x 256 thr; wg covers 32 g's; 8 w-slices of 64 reduced via LDS.
__global__ __launch_bounds__(256)
void reduce_squash(const float* __restrict__ partial, const float* __restrict__ bias,
                   float scale, const float* __restrict__ prev,
                   float* __restrict__ out, float* __restrict__ outsum)
{
    const int t  = threadIdx.x;
    const int g  = blockIdx.x * 32 + (t & 31);   // b*512 + o
    const int sl = t >> 5;                       // w-slice 0..7
    float s = 0.f;
    #pragma unroll 8
    for (int w = sl * 64; w < sl * 64 + 64; ++w)
        s += partial[(size_t)w * (B_ * O_) + g];
    __shared__ float red[256];
    red[t] = s;
    __syncthreads();
    if (t < 32) {
        float v = red[t];
        #pragma unroll
        for (int r = 1; r < 8; ++r) v += red[t + 32 * r];
        const float p = fmaf(v, scale, bias[g & (O_ - 1)]);
        float nn = p * p;
        nn += __shfl_xor(nn, 1);
        nn += __shfl_xor(nn, 2);
        nn += __shfl_xor(nn, 4);
        nn += __shfl_xor(nn, 8);
        const float a = p * sqrtf(nn) / (1.f + nn);
        out[g] = a;
        if (outsum) outsum[g] = a + prev[g];
    }
}

extern "C" void kernel_launch(void* const* d_in, const int* in_sizes, int n_in,
                              void* d_out, int out_size, void* d_ws, size_t ws_size,
                              hipStream_t stream) {
    const float* x    = (const float*)d_in[0];   // [32,2048,16]
    const float* W    = (const float*)d_in[1];   // [2048,16,512]
    const float* bias = (const float*)d_in[2];   // [512]
    float* out = (float*)d_out;                  // [32,512]

    float* partial = (float*)d_ws;                       // 512*32*512 f32 = 33.5 MB
    float* act0    = partial + (size_t)NG_ * B_ * O_;    // 64 KB
    float* act1    = act0 + B_ * O_;                     // 64 KB
    float* actsum  = act1 + B_ * O_;                     // 64 KB

    sweep_kernel<0><<<NG_, 256, 0, stream>>>(x, W, nullptr, partial);
    reduce_squash<<<512, 256, 0, stream>>>(partial, bias, 1.f / 32.f, nullptr, act0, nullptr);
    sweep_kernel<1><<<NG_, 256, 0, stream>>>(x, W, act0, partial);
    reduce_squash<<<512, 256, 0, stream>>>(partial, bias, 1.f, act0, act1, actsum);
    sweep_kernel<2><<<NG_, 256, 0, stream>>>(x, W, actsum, partial);
    reduce_squash<<<512, 256, 0, stream>>>(partial, bias, 1.f, nullptr, out, nullptr);
}

// Round 12
// 200.204 us; speedup vs baseline: 1.2187x; 1.2187x over previous
//
#include <hip/hip_runtime.h>

// CapsuleLayer dynamic routing, MI355X. R15: R13 + counted-vmcnt raw barriers.
//  - R14 (8b/wave) spilled (VGPR cap 128 vs 128+ live): reverted. R13 base.
//  - R13's residual stall: __syncthreads emits s_waitcnt vmcnt(0) lgkmcnt(0)
//    -> every iter drains the glds staging queue (the documented ~20%
//    structural stall) and each iter's first FMA waits ~300cyc on xs s_loads.
//  - R15 schedule per ii (T3/T4 minimum form, 2 raw barriers, no drain):
//      compute(sW[ii&1])            // ds windows + FMA
//      issue xs(ii+1) s_loads       // land during barriers/stage
//      s_barrier                    // all waves done READING sW[ii&1]
//      if (ii+2<IC) { stage(ii+2 -> sW[ii&1]); s_waitcnt vmcnt(8); }
//      else         {                           s_waitcnt vmcnt(0); }
//      s_barrier                    // sW[(ii+1)&1] ready for everyone
//      epilogue(i)                  // softmax/accum, VALU-only
//    vmcnt(8) waits only stage(ii+1)'s 8 glds; stage(ii+2) stays in flight.
//    sched_barrier(0) after each wait/barrier pins ordering (rule #18).
//  - Everything else R13-verbatim: 4b/wave, bh-split, IC=8, glds dwordx4
//    dbuf w/ pre-swizzled source, XCD-pair swizzle, as_=a0+a1 fold.
//
// Lane layout: lane l owns d = l>>1, h = l&1, outputs o = d*16 + h*8 + j.
// a-half combine: shfl_xor(1); softmax over D: shfl_xor {2,4,8,16,32}.
// LDS W layout (per half): float idx = jq*4096 + k*256 + (d*2+h)*4 + (j&3).

#define B_  32
#define I_  2048
#define K_  16
#define O_  512
#define NG_ 256   // i-groups (partial-buffer leading dim)
#define IC_ 8     // i's per group

#define GLB(p)  ((const __attribute__((address_space(1))) void*)(p))
#define LDSP(p) ((__attribute__((address_space(3))) void*)(p))

template<int PASS>
__global__ __launch_bounds__(256, 2)
void sweep_kernel(const float* __restrict__ x, const float* __restrict__ W,
                  const float* __restrict__ act0_g, const float* __restrict__ act1_g,
                  float* __restrict__ partial)
{
    const int tid  = threadIdx.x;
    const int lane = tid & 63;
    const int wave = tid >> 6;              // 0..3
    const int bid  = blockIdx.x;
    // XCD-pair swizzle: xcd = bid&7 (round-robin), pair differs only in bit 3
    const int ig   = (bid & 7) * 32 + (bid >> 4);   // 0..255
    const int bh   = (bid >> 3) & 1;                 // batch half
    const int d    = lane >> 1;             // 0..31
    const int h    = lane & 1;
    const int obase = d * 16 + h * 8;       // lane's first o

    // wave-uniform batch base (forces SGPR so x loads go scalar)
    const int wv    = __builtin_amdgcn_readfirstlane(wave);
    const int bbase = bh * 16 + wv * 4;

    __shared__ float sW[2][K_ * O_];        // 2 x 32 KB, permuted W[i] tiles

    // per-lane pre-swizzled source byte offsets: slot s -> global float4 f
    int voff[8];
    #pragma unroll
    for (int c = 0; c < 8; ++c) {
        const int s = c * 256 + wave * 64 + lane;       // 16B slot index
        const int f = ((s >> 10) & 1) | ((s & 1) << 1)
                    | (((s >> 1) & 31) << 2) | (((s >> 6) & 15) << 7);
        voff[c] = f << 4;                               // byte offset
    }

    float facc[4][8];
    #pragma unroll
    for (int bb = 0; bb < 4; ++bb)
        #pragma unroll
        for (int j = 0; j < 8; ++j) facc[bb][j] = 0.f;

    // as_ = a0 (PASS1) or a0+a1 (PASS2): round-2 logits = V.(a0+a1)
    float as_[4][8];
    if (PASS >= 1) {
        #pragma unroll
        for (int bb = 0; bb < 4; ++bb) {
            const float4* p = (const float4*)(act0_g + (bbase + bb) * O_ + obase);
            float4 f0 = p[0], f1 = p[1];
            as_[bb][0]=f0.x; as_[bb][1]=f0.y; as_[bb][2]=f0.z; as_[bb][3]=f0.w;
            as_[bb][4]=f1.x; as_[bb][5]=f1.y; as_[bb][6]=f1.z; as_[bb][7]=f1.w;
            if (PASS == 2) {
                const float4* q = (const float4*)(act1_g + (bbase + bb) * O_ + obase);
                float4 g0 = q[0], g1 = q[1];
                as_[bb][0]+=g0.x; as_[bb][1]+=g0.y; as_[bb][2]+=g0.z; as_[bb][3]+=g0.w;
                as_[bb][4]+=g1.x; as_[bb][5]+=g1.y; as_[bb][6]+=g1.z; as_[bb][7]+=g1.w;
            }
        }
    }

    const size_t igbase = (size_t)(ig * IC_) * (K_ * O_);

    // xs for current i (wave-uniform scalar loads -> SGPRs)
    float xs[4][16];
    {
        const int i = ig * IC_;
        #pragma unroll
        for (int bb = 0; bb < 4; ++bb) {
            const float4* xp = (const float4*)(x + ((size_t)(bbase + bb) * I_ + i) * K_);
            #pragma unroll
            for (int q = 0; q < 4; ++q) {
                float4 v = xp[q];
                xs[bb][4*q+0]=v.x; xs[bb][4*q+1]=v.y; xs[bb][4*q+2]=v.z; xs[bb][4*q+3]=v.w;
            }
        }
    }

    // prologue: stage tiles 0 and 1; wait only tile 0 (vmcnt(8))
    #pragma unroll
    for (int c = 0; c < 8; ++c)
        __builtin_amdgcn_global_load_lds(GLB((const char*)(W) + igbase * 4 + voff[c]),
            LDSP(&sW[0][(c * 256 + wave * 64) * 4]), 16, 0, 0);
    #pragma unroll
    for (int c = 0; c < 8; ++c)
        __builtin_amdgcn_global_load_lds(GLB((const char*)(W) + (igbase + K_ * O_) * 4 + voff[c]),
            LDSP(&sW[1][(c * 256 + wave * 64) * 4]), 16, 0, 0);
    asm volatile("s_waitcnt vmcnt(8)" ::: "memory");
    __builtin_amdgcn_sched_barrier(0);
    __builtin_amdgcn_s_barrier();
    __builtin_amdgcn_sched_barrier(0);

    #pragma unroll 1
    for (int ii = 0; ii < IC_; ++ii) {
        const int i = ig * IC_ + ii;
        const float* cbuf = sW[ii & 1];

        // ---- compute: two half-k phases of {16 ds_read_b128 window -> FMA}
        float V[4][8];
        #pragma unroll
        for (int bb = 0; bb < 4; ++bb)
            #pragma unroll
            for (int j = 0; j < 8; ++j) V[bb][j] = 0.f;

        #pragma unroll
        for (int kh = 0; kh < 2; ++kh) {
            float4 wr0[8], wr1[8];
            #pragma unroll
            for (int kq = 0; kq < 8; ++kq) {
                const int k = kh * 8 + kq;
                wr0[kq] = *(const float4*)&cbuf[k * 256 + lane * 4];
                wr1[kq] = *(const float4*)&cbuf[4096 + k * 256 + lane * 4];
            }
            #pragma unroll
            for (int kq = 0; kq < 8; ++kq) {
                const int k = kh * 8 + kq;
                const float w[8] = {wr0[kq].x, wr0[kq].y, wr0[kq].z, wr0[kq].w,
                                    wr1[kq].x, wr1[kq].y, wr1[kq].z, wr1[kq].w};
                #pragma unroll
                for (int bb = 0; bb < 4; ++bb) {
                    const float xb = xs[bb][k];
                    #pragma unroll
                    for (int j = 0; j < 8; ++j) V[bb][j] = fmaf(xb, w[j], V[bb][j]);
                }
            }
        }

        // ---- xs prefetch for ii+1: s_loads fly during barriers/stage
        if (ii + 1 < IC_) {
            #pragma unroll
            for (int bb = 0; bb < 4; ++bb) {
                const float4* xp = (const float4*)(x + ((size_t)(bbase + bb) * I_ + (i + 1)) * K_);
                #pragma unroll
                for (int q = 0; q < 4; ++q) {
                    float4 v = xp[q];
                    xs[bb][4*q+0]=v.x; xs[bb][4*q+1]=v.y; xs[bb][4*q+2]=v.z; xs[bb][4*q+3]=v.w;
                }
            }
        }

        // ---- barrier 1: all waves done reading sW[ii&1] -> safe to overwrite
        __builtin_amdgcn_s_barrier();
        __builtin_amdgcn_sched_barrier(0);
        if (ii + 2 < IC_) {
            const char* gb = (const char*)(W + igbase + (size_t)(ii + 2) * (K_ * O_));
            float* nbuf = sW[ii & 1];
            #pragma unroll
            for (int c = 0; c < 8; ++c)
                __builtin_amdgcn_global_load_lds(GLB(gb + voff[c]),
                    LDSP(&nbuf[(c * 256 + wave * 64) * 4]), 16, 0, 0);
            asm volatile("s_waitcnt vmcnt(8)" ::: "memory");   // tile ii+1 done
        } else {
            asm volatile("s_waitcnt vmcnt(0)" ::: "memory");   // drain tail
        }
        __builtin_amdgcn_sched_barrier(0);
        // ---- barrier 2: sW[(ii+1)&1] ready for everyone
        __builtin_amdgcn_s_barrier();
        __builtin_amdgcn_sched_barrier(0);

        // ---- epilogue for i (VALU-only, overlaps other waves' next compute)
        #pragma unroll
        for (int bb = 0; bb < 4; ++bb) {
            if (PASS == 0) {
                #pragma unroll
                for (int j = 0; j < 8; ++j) facc[bb][j] += V[bb][j];
            } else {
                float p0 = 0.f;
                #pragma unroll
                for (int j = 0; j < 8; ++j) p0 = fmaf(V[bb][j], as_[bb][j], p0);
                p0 += __shfl_xor(p0, 1);        // combine the two a-halves
                const float e = __expf(p0);
                float s = e;
                s += __shfl_xor(s, 2);
                s += __shfl_xor(s, 4);
                s += __shfl_xor(s, 8);
                s += __shfl_xor(s, 16);
                s += __shfl_xor(s, 32);
                const float r = e * __builtin_amdgcn_rcpf(s);
                #pragma unroll
                for (int j = 0; j < 8; ++j)
                    facc[bb][j] = fmaf(r, V[bb][j], facc[bb][j]);
            }
        }
    }

    // flush per-(ig) partials
    #pragma unroll
    for (int bb = 0; bb < 4; ++bb) {
        const int b = bbase + bb;
        float4* dst = (float4*)(partial + ((size_t)ig * B_ + b) * O_ + obase);
        dst[0] = make_float4(facc[bb][0], facc[bb][1], facc[bb][2], facc[bb][3]);
        dst[1] = make_float4(facc[bb][4], facc[bb][5], facc[bb][6], facc[bb][7]);
    }
}

// sum NG_ partials -> *scale + bias -> squash over A -> out
__global__ __launch_bounds__(256)
void reduce_squash(const float* __restrict__ partial, const float* __restrict__ bias,
                   float scale, float* __restrict__ out)
{
    const int t  = threadIdx.x;
    const int g  = blockIdx.x * 32 + (t & 31);   // b*512 + o
    const int sl = t >> 5;                       // w-slice 0..7
    float s = 0.f;
    #pragma unroll
    for (int w = sl * 32; w < sl * 32 + 32; ++w)
        s += partial[(size_t)w * (B_ * O_) + g];
    __shared__ float red[256];
    red[t] = s;
    __syncthreads();
    if (t < 32) {
        float v = red[t];
        #pragma unroll
        for (int r = 1; r < 8; ++r) v += red[t + 32 * r];
        const float p = fmaf(v, scale, bias[g & (O_ - 1)]);
        float nn = p * p;
        nn += __shfl_xor(nn, 1);
        nn += __shfl_xor(nn, 2);
        nn += __shfl_xor(nn, 4);
        nn += __shfl_xor(nn, 8);
        out[g] = p * sqrtf(nn) / (1.f + nn);
    }
}

extern "C" void kernel_launch(void* const* d_in, const int* in_sizes, int n_in,
                              void* d_out, int out_size, void* d_ws, size_t ws_size,
                              hipStream_t stream) {
    const float* x    = (const float*)d_in[0];   // [32,2048,16]
    const float* W    = (const float*)d_in[1];   // [2048,16,512]
    const float* bias = (const float*)d_in[2];   // [512]
    float* out = (float*)d_out;                  // [32,512]

    float* partial = (float*)d_ws;                       // NG_*32*512 f32 = 16.8 MB
    float* act0    = partial + (size_t)NG_ * B_ * O_;    // 64 KB
    float* act1    = act0 + B_ * O_;                     // 64 KB

    sweep_kernel<0><<<NG_ * 2, 256, 0, stream>>>(x, W, nullptr, nullptr, partial);
    reduce_squash<<<512, 256, 0, stream>>>(partial, bias, 1.f / 32.f, act0);
    sweep_kernel<1><<<NG_ * 2, 256, 0, stream>>>(x, W, act0, nullptr, partial);
    reduce_squash<<<512, 256, 0, stream>>>(partial, bias, 1.f, act1);
    sweep_kernel<2><<<NG_ * 2, 256, 0, stream>>>(x, W, act0, act1, partial);
    reduce_squash<<<512, 256, 0, stream>>>(partial, bias, 1.f, out);
}